// Round 1
// baseline (4043.462 us; speedup 1.0000x reference)
//
#include <hip/hip_runtime.h>

#define N_NODES 50000
#define N_EDGES 800000
#define D_FEAT 96
#define HOP_NUM 4

// 32 threads per edge; lanes 0..23 each handle one float4 chunk of the 96-dim feature.
__global__ void spmm_edge_kernel(const float* __restrict__ feat, int feat_stride,
                                 const float* __restrict__ dnorm,
                                 const int* __restrict__ src,
                                 const int* __restrict__ dst,
                                 float* __restrict__ acc) {
    long long tid = (long long)blockIdx.x * blockDim.x + threadIdx.x;
    int e = (int)(tid >> 5);
    int c = (int)(tid & 31);
    if (e >= N_EDGES || c >= 24) return;
    int s = src[e];
    int t = dst[e];
    float w = dnorm[s] * dnorm[t];
    const float4* fp = (const float4*)(feat + (long long)s * feat_stride);
    float4 v = fp[c];
    float* ap = acc + (long long)t * D_FEAT + c * 4;
    atomicAdd(ap + 0, v.x * w);
    atomicAdd(ap + 1, v.y * w);
    atomicAdd(ap + 2, v.z * w);
    atomicAdd(ap + 3, v.w * w);
}

// out[n, hop*96 + c*4 .. +3] = acc*r + (1-r)*prev ; out points at d_out + hop*96.
__global__ void combine_kernel(const float* __restrict__ acc,
                               const float* __restrict__ prev, int prev_stride,
                               const float* __restrict__ layer_regular, int hop,
                               float* __restrict__ out) {
    int tid = blockIdx.x * blockDim.x + threadIdx.x;
    if (tid >= N_NODES * 24) return;
    int n = tid / 24;
    int c = tid % 24;
    float r = layer_regular[hop];
    float4 a = ((const float4*)(acc + (long long)n * D_FEAT))[c];
    float4 p = ((const float4*)(prev + (long long)n * prev_stride))[c];
    float4 o;
    o.x = a.x * r + (1.0f - r) * p.x;
    o.y = a.y * r + (1.0f - r) * p.y;
    o.z = a.z * r + (1.0f - r) * p.z;
    o.w = a.w * r + (1.0f - r) * p.w;
    ((float4*)(out + (long long)n * (HOP_NUM * D_FEAT)))[c] = o;
}

extern "C" void kernel_launch(void* const* d_in, const int* in_sizes, int n_in,
                              void* d_out, int out_size, void* d_ws, size_t ws_size,
                              hipStream_t stream) {
    const float* h    = (const float*)d_in[0];
    const float* dn   = (const float*)d_in[1];
    const int*   src  = (const int*)d_in[2];
    const int*   dst  = (const int*)d_in[3];
    const float* lr   = (const float*)d_in[4];
    float* out = (float*)d_out;
    float* acc = (float*)d_ws;  // N_NODES * D_FEAT floats = 19.2 MB

    const int edge_threads = N_EDGES * 32;
    const int edge_blocks  = (edge_threads + 255) / 256;
    const int comb_threads = N_NODES * 24;
    const int comb_blocks  = (comb_threads + 255) / 256;

    for (int hop = 0; hop < HOP_NUM; ++hop) {
        hipMemsetAsync(acc, 0, (size_t)N_NODES * D_FEAT * sizeof(float), stream);
        const float* prev = (hop == 0) ? h : (out + (hop - 1) * D_FEAT);
        int prev_stride   = (hop == 0) ? D_FEAT : (HOP_NUM * D_FEAT);
        spmm_edge_kernel<<<edge_blocks, 256, 0, stream>>>(prev, prev_stride, dn, src, dst, acc);
        combine_kernel<<<comb_blocks, 256, 0, stream>>>(acc, prev, prev_stride, lr, hop,
                                                        out + hop * D_FEAT);
    }
}

// Round 2
// 390.963 us; speedup vs baseline: 10.3423x; 10.3423x over previous
//
#include <hip/hip_runtime.h>

#define N_NODES 50000
#define N_EDGES 800000
#define D_FEAT 96
#define HOP_NUM 4
#define OUT_STRIDE (HOP_NUM * D_FEAT)

// ---------- CSR build (once per launch) ----------

__global__ void hist_kernel(const int* __restrict__ dst, int* __restrict__ deg) {
    int e = blockIdx.x * blockDim.x + threadIdx.x;
    if (e >= N_EDGES) return;
    atomicAdd(&deg[dst[e]], 1);
}

// Single-block exclusive scan over deg -> off; zeroes deg for reuse as scatter cursor.
__global__ void scan_kernel(int* __restrict__ deg, int* __restrict__ off) {
    __shared__ int part[1024];
    const int tid = threadIdx.x;
    const int CHUNK = (N_NODES + 1023) / 1024;
    int beg = tid * CHUNK;
    int end = min(beg + CHUNK, N_NODES);
    int sum = 0;
    for (int i = beg; i < end; ++i) sum += deg[i];
    part[tid] = sum;
    __syncthreads();
    for (int ofs = 1; ofs < 1024; ofs <<= 1) {
        int v = (tid >= ofs) ? part[tid - ofs] : 0;
        __syncthreads();
        part[tid] += v;
        __syncthreads();
    }
    int run = (tid > 0) ? part[tid - 1] : 0;
    for (int i = beg; i < end; ++i) {
        int d = deg[i];
        off[i] = run;
        run += d;
        deg[i] = 0;  // becomes scatter cursor
    }
    if (tid == 1023) off[N_NODES] = part[1023];
}

__global__ void scatter_kernel(const int* __restrict__ src, const int* __restrict__ dst,
                               const float* __restrict__ dn,
                               const int* __restrict__ off, int* __restrict__ cursor,
                               int* __restrict__ ssrc, float* __restrict__ sw) {
    int e = blockIdx.x * blockDim.x + threadIdx.x;
    if (e >= N_EDGES) return;
    int t = dst[e];
    int s = src[e];
    float w = dn[s] * dn[t];
    int p = atomicAdd(&cursor[t], 1);
    int idx = off[t] + p;
    ssrc[idx] = s;
    sw[idx] = w;
}

// ---------- fused per-hop SpMM + residual blend ----------
// 32-lane group per dst node; lanes 0..23 each own one float4 of the 96 channels.
__global__ void spmm_gather_kernel(const float* __restrict__ feat, int feat_stride,
                                   const int* __restrict__ off,
                                   const int* __restrict__ ssrc,
                                   const float* __restrict__ sw,
                                   const float* __restrict__ lr, int hop,
                                   float* __restrict__ out) {
    int gid = (blockIdx.x * blockDim.x + threadIdx.x) >> 5;
    int lane = threadIdx.x & 31;
    if (gid >= N_NODES || lane >= 24) return;
    int beg = off[gid];
    int end = off[gid + 1];

    float4 acc = make_float4(0.f, 0.f, 0.f, 0.f);
    int k = beg;
    int s_next = 0;
    float w_next = 0.f;
    if (k < end) { s_next = ssrc[k]; w_next = sw[k]; }
    for (; k < end; ++k) {
        int s = s_next;
        float w = w_next;
        if (k + 1 < end) { s_next = ssrc[k + 1]; w_next = sw[k + 1]; }
        float4 v = ((const float4*)(feat + (long long)s * feat_stride))[lane];
        acc.x += v.x * w;
        acc.y += v.y * w;
        acc.z += v.z * w;
        acc.w += v.w * w;
    }

    float r = lr[hop];
    float4 p = ((const float4*)(feat + (long long)gid * feat_stride))[lane];
    float4 o;
    o.x = acc.x * r + (1.0f - r) * p.x;
    o.y = acc.y * r + (1.0f - r) * p.y;
    o.z = acc.z * r + (1.0f - r) * p.z;
    o.w = acc.w * r + (1.0f - r) * p.w;
    ((float4*)(out + (long long)gid * OUT_STRIDE))[lane] = o;
}

extern "C" void kernel_launch(void* const* d_in, const int* in_sizes, int n_in,
                              void* d_out, int out_size, void* d_ws, size_t ws_size,
                              hipStream_t stream) {
    const float* h   = (const float*)d_in[0];
    const float* dn  = (const float*)d_in[1];
    const int*   src = (const int*)d_in[2];
    const int*   dst = (const int*)d_in[3];
    const float* lr  = (const float*)d_in[4];
    float* out = (float*)d_out;

    // workspace carve-up
    char* base = (char*)d_ws;
    int* off    = (int*)base;                         base += (N_NODES + 1) * sizeof(int);
    int* deg    = (int*)base;                         base += N_NODES * sizeof(int);
    int* ssrc   = (int*)base;                         base += N_EDGES * sizeof(int);
    float* sw   = (float*)base;                       base += N_EDGES * sizeof(float);

    const int EB = (N_EDGES + 255) / 256;

    // build CSR by dst (once per launch)
    hipMemsetAsync(deg, 0, N_NODES * sizeof(int), stream);
    hist_kernel<<<EB, 256, 0, stream>>>(dst, deg);
    scan_kernel<<<1, 1024, 0, stream>>>(deg, off);
    scatter_kernel<<<EB, 256, 0, stream>>>(src, dst, dn, off, deg, ssrc, sw);

    // 4 fused hops
    const int GROUPS_PER_BLOCK = 8;  // 256 threads = 8 x 32-lane groups
    const int HB = (N_NODES + GROUPS_PER_BLOCK - 1) / GROUPS_PER_BLOCK;
    for (int hop = 0; hop < HOP_NUM; ++hop) {
        const float* prev = (hop == 0) ? h : (out + (hop - 1) * D_FEAT);
        int prev_stride   = (hop == 0) ? D_FEAT : OUT_STRIDE;
        spmm_gather_kernel<<<HB, 256, 0, stream>>>(prev, prev_stride, off, ssrc, sw,
                                                   lr, hop, out + hop * D_FEAT);
    }
}

// Round 3
// 286.249 us; speedup vs baseline: 14.1257x; 1.3658x over previous
//
#include <hip/hip_runtime.h>

#define N_NODES 50000
#define N_EDGES 800000
#define D_FEAT 96
#define HOP_NUM 4
#define OUT_STRIDE (HOP_NUM * D_FEAT)
#define SCAN_B 256
#define NBLK_SCAN ((N_NODES + SCAN_B - 1) / SCAN_B)  // 196

struct Edge { int s; float w; };

// ---------- CSR build (once per launch) ----------

__global__ void hist_kernel(const int* __restrict__ dst, int* __restrict__ deg) {
    int e = blockIdx.x * blockDim.x + threadIdx.x;
    if (e >= N_EDGES) return;
    atomicAdd(&deg[dst[e]], 1);
}

// Phase A: per-block exclusive scan of deg into off (local), block totals -> partials.
__global__ void scanA_kernel(const int* __restrict__ deg, int* __restrict__ off,
                             int* __restrict__ partials) {
    int i = blockIdx.x * SCAN_B + threadIdx.x;
    int v = (i < N_NODES) ? deg[i] : 0;
    int lane = threadIdx.x & 63;
    int wid  = threadIdx.x >> 6;
    int x = v;
    #pragma unroll
    for (int o = 1; o < 64; o <<= 1) {
        int y = __shfl_up(x, o, 64);
        if (lane >= o) x += y;
    }
    __shared__ int wtot[SCAN_B / 64];
    if (lane == 63) wtot[wid] = x;
    __syncthreads();
    int wbase = 0;
    #pragma unroll
    for (int w = 0; w < SCAN_B / 64; ++w) wbase += (w < wid) ? wtot[w] : 0;
    if (i < N_NODES) off[i] = wbase + x - v;
    if (threadIdx.x == SCAN_B - 1) partials[blockIdx.x] = wbase + x;
}

// Phase B: single block scans the 196 partials (exclusive, in place).
__global__ void scanB_kernel(int* __restrict__ partials) {
    int tid = threadIdx.x;  // 256 threads
    int v = (tid < NBLK_SCAN) ? partials[tid] : 0;
    int lane = tid & 63;
    int wid  = tid >> 6;
    int x = v;
    #pragma unroll
    for (int o = 1; o < 64; o <<= 1) {
        int y = __shfl_up(x, o, 64);
        if (lane >= o) x += y;
    }
    __shared__ int wtot[SCAN_B / 64];
    if (lane == 63) wtot[wid] = x;
    __syncthreads();
    int wbase = 0;
    #pragma unroll
    for (int w = 0; w < SCAN_B / 64; ++w) wbase += (w < wid) ? wtot[w] : 0;
    if (tid < NBLK_SCAN) partials[tid] = wbase + x - v;
}

// Phase C: add block bases; zero the scatter cursor; off[N] = E (known).
__global__ void scanC_kernel(int* __restrict__ off, const int* __restrict__ partials,
                             int* __restrict__ cursor) {
    int i = blockIdx.x * SCAN_B + threadIdx.x;
    if (i < N_NODES) {
        off[i] += partials[blockIdx.x];
        cursor[i] = 0;
    }
    if (i == 0) off[N_NODES] = N_EDGES;
}

__global__ void scatter_kernel(const int* __restrict__ src, const int* __restrict__ dst,
                               const float* __restrict__ dn,
                               const int* __restrict__ off, int* __restrict__ cursor,
                               Edge* __restrict__ edges) {
    int e = blockIdx.x * blockDim.x + threadIdx.x;
    if (e >= N_EDGES) return;
    int t = dst[e];
    int s = src[e];
    float w = dn[s] * dn[t];
    int p = atomicAdd(&cursor[t], 1);
    Edge ed; ed.s = s; ed.w = w;
    edges[off[t] + p] = ed;
}

// ---------- fused per-hop SpMM + residual blend ----------
// 32-lane group per dst node; lanes 0..23 own one float4 of the 96 channels.
// Edges batch-loaded 32 at a time and broadcast via shfl.
__global__ void spmm_gather_kernel(const float* __restrict__ feat, int feat_stride,
                                   const int* __restrict__ off,
                                   const Edge* __restrict__ edges,
                                   const float* __restrict__ lr, int hop,
                                   float* __restrict__ out) {
    int gid = (blockIdx.x * blockDim.x + threadIdx.x) >> 5;
    int lane = threadIdx.x & 31;
    if (gid >= N_NODES) return;
    int beg = off[gid];
    int end = off[gid + 1];

    float4 acc = make_float4(0.f, 0.f, 0.f, 0.f);
    for (int b = beg; b < end; b += 32) {
        int m = min(32, end - b);
        int s_l = 0; float w_l = 0.f;
        if (lane < m) {
            Edge ed = edges[b + lane];
            s_l = ed.s; w_l = ed.w;
        }
        for (int j = 0; j < m; ++j) {
            int   s = __shfl(s_l, j, 32);
            float w = __shfl(w_l, j, 32);
            if (lane < 24) {
                float4 v = ((const float4*)(feat + (long long)s * feat_stride))[lane];
                acc.x = fmaf(v.x, w, acc.x);
                acc.y = fmaf(v.y, w, acc.y);
                acc.z = fmaf(v.z, w, acc.z);
                acc.w = fmaf(v.w, w, acc.w);
            }
        }
    }

    if (lane < 24) {
        float r = lr[hop];
        float4 p = ((const float4*)(feat + (long long)gid * feat_stride))[lane];
        float4 o;
        o.x = acc.x * r + (1.0f - r) * p.x;
        o.y = acc.y * r + (1.0f - r) * p.y;
        o.z = acc.z * r + (1.0f - r) * p.z;
        o.w = acc.w * r + (1.0f - r) * p.w;
        ((float4*)(out + (long long)gid * OUT_STRIDE))[lane] = o;
    }
}

extern "C" void kernel_launch(void* const* d_in, const int* in_sizes, int n_in,
                              void* d_out, int out_size, void* d_ws, size_t ws_size,
                              hipStream_t stream) {
    const float* h   = (const float*)d_in[0];
    const float* dn  = (const float*)d_in[1];
    const int*   src = (const int*)d_in[2];
    const int*   dst = (const int*)d_in[3];
    const float* lr  = (const float*)d_in[4];
    float* out = (float*)d_out;

    // workspace carve-up (edges first to keep 8-byte alignment)
    char* base = (char*)d_ws;
    Edge* edges   = (Edge*)base;  base += (size_t)N_EDGES * sizeof(Edge);
    int* off      = (int*)base;   base += (N_NODES + 1) * sizeof(int);
    int* deg      = (int*)base;   base += N_NODES * sizeof(int);
    int* partials = (int*)base;   base += NBLK_SCAN * sizeof(int);

    const int EB = (N_EDGES + 255) / 256;

    hipMemsetAsync(deg, 0, N_NODES * sizeof(int), stream);
    hist_kernel<<<EB, 256, 0, stream>>>(dst, deg);
    scanA_kernel<<<NBLK_SCAN, SCAN_B, 0, stream>>>(deg, off, partials);
    scanB_kernel<<<1, SCAN_B, 0, stream>>>(partials);
    scanC_kernel<<<NBLK_SCAN, SCAN_B, 0, stream>>>(off, partials, deg);
    scatter_kernel<<<EB, 256, 0, stream>>>(src, dst, dn, off, deg, edges);

    // 4 fused hops
    const int GROUPS_PER_BLOCK = 8;  // 256 threads = 8 x 32-lane groups
    const int HB = (N_NODES + GROUPS_PER_BLOCK - 1) / GROUPS_PER_BLOCK;
    for (int hop = 0; hop < HOP_NUM; ++hop) {
        const float* prev = (hop == 0) ? h : (out + (hop - 1) * D_FEAT);
        int prev_stride   = (hop == 0) ? D_FEAT : OUT_STRIDE;
        spmm_gather_kernel<<<HB, 256, 0, stream>>>(prev, prev_stride, off, edges,
                                                   lr, hop, out + hop * D_FEAT);
    }
}

// Round 4
// 275.352 us; speedup vs baseline: 14.6847x; 1.0396x over previous
//
#include <hip/hip_runtime.h>

#define N_NODES 50000
#define N_EDGES 800000
#define D_FEAT 96
#define HOP_NUM 4
#define OUT_STRIDE (HOP_NUM * D_FEAT)
#define SCAN_B 256
#define NBLK_SCAN ((N_NODES + SCAN_B - 1) / SCAN_B)  // 196

struct Edge { int s; float w; };

// ---------- CSR build (once per launch) ----------

__global__ void hist_kernel(const int* __restrict__ dst, int* __restrict__ deg) {
    int e = blockIdx.x * blockDim.x + threadIdx.x;
    if (e >= N_EDGES) return;
    atomicAdd(&deg[dst[e]], 1);
}

// Phase A: per-block exclusive scan of deg into off (local), block totals -> partials.
__global__ void scanA_kernel(const int* __restrict__ deg, int* __restrict__ off,
                             int* __restrict__ partials) {
    int i = blockIdx.x * SCAN_B + threadIdx.x;
    int v = (i < N_NODES) ? deg[i] : 0;
    int lane = threadIdx.x & 63;
    int wid  = threadIdx.x >> 6;
    int x = v;
    #pragma unroll
    for (int o = 1; o < 64; o <<= 1) {
        int y = __shfl_up(x, o, 64);
        if (lane >= o) x += y;
    }
    __shared__ int wtot[SCAN_B / 64];
    if (lane == 63) wtot[wid] = x;
    __syncthreads();
    int wbase = 0;
    #pragma unroll
    for (int w = 0; w < SCAN_B / 64; ++w) wbase += (w < wid) ? wtot[w] : 0;
    if (i < N_NODES) off[i] = wbase + x - v;
    if (threadIdx.x == SCAN_B - 1) partials[blockIdx.x] = wbase + x;
}

// Phase B: single block scans the 196 partials (exclusive, in place).
__global__ void scanB_kernel(int* __restrict__ partials) {
    int tid = threadIdx.x;  // 256 threads
    int v = (tid < NBLK_SCAN) ? partials[tid] : 0;
    int lane = tid & 63;
    int wid  = tid >> 6;
    int x = v;
    #pragma unroll
    for (int o = 1; o < 64; o <<= 1) {
        int y = __shfl_up(x, o, 64);
        if (lane >= o) x += y;
    }
    __shared__ int wtot[SCAN_B / 64];
    if (lane == 63) wtot[wid] = x;
    __syncthreads();
    int wbase = 0;
    #pragma unroll
    for (int w = 0; w < SCAN_B / 64; ++w) wbase += (w < wid) ? wtot[w] : 0;
    if (tid < NBLK_SCAN) partials[tid] = wbase + x - v;
}

// Phase C: add block bases; zero the scatter cursor; off[N] = E (known).
__global__ void scanC_kernel(int* __restrict__ off, const int* __restrict__ partials,
                             int* __restrict__ cursor) {
    int i = blockIdx.x * SCAN_B + threadIdx.x;
    if (i < N_NODES) {
        off[i] += partials[blockIdx.x];
        cursor[i] = 0;
    }
    if (i == 0) off[N_NODES] = N_EDGES;
}

__global__ void scatter_kernel(const int* __restrict__ src, const int* __restrict__ dst,
                               const float* __restrict__ dn,
                               const int* __restrict__ off, int* __restrict__ cursor,
                               Edge* __restrict__ edges) {
    int e = blockIdx.x * blockDim.x + threadIdx.x;
    if (e >= N_EDGES) return;
    int t = dst[e];
    int s = src[e];
    float w = dn[s] * dn[t];
    int p = atomicAdd(&cursor[t], 1);
    Edge ed; ed.s = s; ed.w = w;
    edges[off[t] + p] = ed;
}

// ---------- fused per-hop SpMM + residual blend ----------
// 32-lane group per dst node; lanes 0..23 own one float4 of the 96 channels.
// Edge loop unrolled x4: 4 independent row-gathers in flight per group.
__global__ void spmm_gather_kernel(const float* __restrict__ feat, int feat_stride,
                                   const int* __restrict__ off,
                                   const Edge* __restrict__ edges,
                                   const float* __restrict__ lr, int hop,
                                   float* __restrict__ out) {
    int gid = (blockIdx.x * blockDim.x + threadIdx.x) >> 5;
    int lane = threadIdx.x & 31;
    if (gid >= N_NODES) return;
    int beg = off[gid];
    int end = off[gid + 1];
    const bool ch = (lane < 24);

    float4 acc = make_float4(0.f, 0.f, 0.f, 0.f);
    for (int b = beg; b < end; b += 32) {
        int m = min(32, end - b);
        int s_l = 0; float w_l = 0.f;
        if (lane < m) {
            Edge ed = edges[b + lane];
            s_l = ed.s; w_l = ed.w;
        }
        int j = 0;
        for (; j + 4 <= m; j += 4) {
            int   s0 = __shfl(s_l, j,     32);
            int   s1 = __shfl(s_l, j + 1, 32);
            int   s2 = __shfl(s_l, j + 2, 32);
            int   s3 = __shfl(s_l, j + 3, 32);
            float w0 = __shfl(w_l, j,     32);
            float w1 = __shfl(w_l, j + 1, 32);
            float w2 = __shfl(w_l, j + 2, 32);
            float w3 = __shfl(w_l, j + 3, 32);
            if (ch) {
                float4 v0 = ((const float4*)(feat + (long long)s0 * feat_stride))[lane];
                float4 v1 = ((const float4*)(feat + (long long)s1 * feat_stride))[lane];
                float4 v2 = ((const float4*)(feat + (long long)s2 * feat_stride))[lane];
                float4 v3 = ((const float4*)(feat + (long long)s3 * feat_stride))[lane];
                acc.x = fmaf(v0.x, w0, fmaf(v1.x, w1, fmaf(v2.x, w2, fmaf(v3.x, w3, acc.x))));
                acc.y = fmaf(v0.y, w0, fmaf(v1.y, w1, fmaf(v2.y, w2, fmaf(v3.y, w3, acc.y))));
                acc.z = fmaf(v0.z, w0, fmaf(v1.z, w1, fmaf(v2.z, w2, fmaf(v3.z, w3, acc.z))));
                acc.w = fmaf(v0.w, w0, fmaf(v1.w, w1, fmaf(v2.w, w2, fmaf(v3.w, w3, acc.w))));
            }
        }
        for (; j < m; ++j) {
            int   s = __shfl(s_l, j, 32);
            float w = __shfl(w_l, j, 32);
            if (ch) {
                float4 v = ((const float4*)(feat + (long long)s * feat_stride))[lane];
                acc.x = fmaf(v.x, w, acc.x);
                acc.y = fmaf(v.y, w, acc.y);
                acc.z = fmaf(v.z, w, acc.z);
                acc.w = fmaf(v.w, w, acc.w);
            }
        }
    }

    if (ch) {
        float r = lr[hop];
        float4 p = ((const float4*)(feat + (long long)gid * feat_stride))[lane];
        float4 o;
        o.x = acc.x * r + (1.0f - r) * p.x;
        o.y = acc.y * r + (1.0f - r) * p.y;
        o.z = acc.z * r + (1.0f - r) * p.z;
        o.w = acc.w * r + (1.0f - r) * p.w;
        ((float4*)(out + (long long)gid * OUT_STRIDE))[lane] = o;
    }
}

extern "C" void kernel_launch(void* const* d_in, const int* in_sizes, int n_in,
                              void* d_out, int out_size, void* d_ws, size_t ws_size,
                              hipStream_t stream) {
    const float* h   = (const float*)d_in[0];
    const float* dn  = (const float*)d_in[1];
    const int*   src = (const int*)d_in[2];
    const int*   dst = (const int*)d_in[3];
    const float* lr  = (const float*)d_in[4];
    float* out = (float*)d_out;

    // workspace carve-up (edges first to keep 8-byte alignment)
    char* base = (char*)d_ws;
    Edge* edges   = (Edge*)base;  base += (size_t)N_EDGES * sizeof(Edge);
    int* off      = (int*)base;   base += (N_NODES + 1) * sizeof(int);
    int* deg      = (int*)base;   base += N_NODES * sizeof(int);
    int* partials = (int*)base;   base += NBLK_SCAN * sizeof(int);

    const int EB = (N_EDGES + 255) / 256;

    hipMemsetAsync(deg, 0, N_NODES * sizeof(int), stream);
    hist_kernel<<<EB, 256, 0, stream>>>(dst, deg);
    scanA_kernel<<<NBLK_SCAN, SCAN_B, 0, stream>>>(deg, off, partials);
    scanB_kernel<<<1, SCAN_B, 0, stream>>>(partials);
    scanC_kernel<<<NBLK_SCAN, SCAN_B, 0, stream>>>(off, partials, deg);
    scatter_kernel<<<EB, 256, 0, stream>>>(src, dst, dn, off, deg, edges);

    // 4 fused hops
    const int GROUPS_PER_BLOCK = 8;  // 256 threads = 8 x 32-lane groups
    const int HB = (N_NODES + GROUPS_PER_BLOCK - 1) / GROUPS_PER_BLOCK;
    for (int hop = 0; hop < HOP_NUM; ++hop) {
        const float* prev = (hop == 0) ? h : (out + (hop - 1) * D_FEAT);
        int prev_stride   = (hop == 0) ? D_FEAT : OUT_STRIDE;
        spmm_gather_kernel<<<HB, 256, 0, stream>>>(prev, prev_stride, off, edges,
                                                   lr, hop, out + hop * D_FEAT);
    }
}

// Round 5
// 218.363 us; speedup vs baseline: 18.5172x; 1.2610x over previous
//
#include <hip/hip_runtime.h>

#define N_NODES 50000
#define N_EDGES 800000
#define D_FEAT 96
#define HOP_NUM 4
#define OUT_STRIDE (HOP_NUM * D_FEAT)
#define SCAN_B 256
#define NBLK_SCAN ((N_NODES + SCAN_B - 1) / SCAN_B)  // 196

struct Edge { int s; float w; };

__device__ __forceinline__ unsigned short f2bf(float x) {
    union { float f; unsigned u; } c; c.f = x;
    unsigned r = (c.u + 0x7FFFu + ((c.u >> 16) & 1u)) >> 16;  // RNE
    return (unsigned short)r;
}
__device__ __forceinline__ float bf2f(unsigned short b) {
    union { unsigned u; float f; } c; c.u = ((unsigned)b) << 16;
    return c.f;
}

// ---------- CSR build (once per launch) ----------

__global__ void hist_kernel(const int* __restrict__ dst, int* __restrict__ deg) {
    int e = blockIdx.x * blockDim.x + threadIdx.x;
    if (e >= N_EDGES) return;
    atomicAdd(&deg[dst[e]], 1);
}

__global__ void scanA_kernel(const int* __restrict__ deg, int* __restrict__ off,
                             int* __restrict__ partials) {
    int i = blockIdx.x * SCAN_B + threadIdx.x;
    int v = (i < N_NODES) ? deg[i] : 0;
    int lane = threadIdx.x & 63;
    int wid  = threadIdx.x >> 6;
    int x = v;
    #pragma unroll
    for (int o = 1; o < 64; o <<= 1) {
        int y = __shfl_up(x, o, 64);
        if (lane >= o) x += y;
    }
    __shared__ int wtot[SCAN_B / 64];
    if (lane == 63) wtot[wid] = x;
    __syncthreads();
    int wbase = 0;
    #pragma unroll
    for (int w = 0; w < SCAN_B / 64; ++w) wbase += (w < wid) ? wtot[w] : 0;
    if (i < N_NODES) off[i] = wbase + x - v;
    if (threadIdx.x == SCAN_B - 1) partials[blockIdx.x] = wbase + x;
}

__global__ void scanB_kernel(int* __restrict__ partials) {
    int tid = threadIdx.x;  // 256 threads
    int v = (tid < NBLK_SCAN) ? partials[tid] : 0;
    int lane = tid & 63;
    int wid  = tid >> 6;
    int x = v;
    #pragma unroll
    for (int o = 1; o < 64; o <<= 1) {
        int y = __shfl_up(x, o, 64);
        if (lane >= o) x += y;
    }
    __shared__ int wtot[SCAN_B / 64];
    if (lane == 63) wtot[wid] = x;
    __syncthreads();
    int wbase = 0;
    #pragma unroll
    for (int w = 0; w < SCAN_B / 64; ++w) wbase += (w < wid) ? wtot[w] : 0;
    if (tid < NBLK_SCAN) partials[tid] = wbase + x - v;
}

__global__ void scanC_kernel(int* __restrict__ off, const int* __restrict__ partials,
                             int* __restrict__ cursor) {
    int i = blockIdx.x * SCAN_B + threadIdx.x;
    if (i < N_NODES) {
        off[i] += partials[blockIdx.x];
        cursor[i] = 0;
    }
    if (i == 0) off[N_NODES] = N_EDGES;
}

__global__ void scatter_kernel(const int* __restrict__ src, const int* __restrict__ dst,
                               const float* __restrict__ dn,
                               const int* __restrict__ off, int* __restrict__ cursor,
                               Edge* __restrict__ edges) {
    int e = blockIdx.x * blockDim.x + threadIdx.x;
    if (e >= N_EDGES) return;
    int t = dst[e];
    int s = src[e];
    float w = dn[s] * dn[t];
    int p = atomicAdd(&cursor[t], 1);
    Edge ed; ed.s = s; ed.w = w;
    edges[off[t] + p] = ed;
}

// seed: f32 features -> bf16 table
__global__ void f32_to_bf16_kernel(const float* __restrict__ in, unsigned short* __restrict__ out) {
    int i = blockIdx.x * blockDim.x + threadIdx.x;
    if (i >= N_NODES * D_FEAT / 4) return;
    float4 v = ((const float4*)in)[i];
    ushort4 o;
    o.x = f2bf(v.x); o.y = f2bf(v.y); o.z = f2bf(v.z); o.w = f2bf(v.w);
    ((ushort4*)out)[i] = o;
}

// ---------- fused per-hop SpMM + residual blend (bf16 gather table) ----------
// 32-lane group per dst node; lanes 0..23 own 4 channels (ushort4 = 8 B).
__global__ void spmm_gather_kernel(const unsigned short* __restrict__ tab,
                                   const int* __restrict__ off,
                                   const Edge* __restrict__ edges,
                                   const float* __restrict__ lr, int hop,
                                   float* __restrict__ out,
                                   unsigned short* __restrict__ tab_next) {
    int gid = (blockIdx.x * blockDim.x + threadIdx.x) >> 5;
    int lane = threadIdx.x & 31;
    if (gid >= N_NODES) return;
    int beg = off[gid];
    int end = off[gid + 1];
    const bool ch = (lane < 24);

    float4 acc = make_float4(0.f, 0.f, 0.f, 0.f);
    for (int b = beg; b < end; b += 32) {
        int m = min(32, end - b);
        int s_l = 0; float w_l = 0.f;
        if (lane < m) {
            Edge ed = edges[b + lane];
            s_l = ed.s; w_l = ed.w;
        }
        int j = 0;
        for (; j + 4 <= m; j += 4) {
            int   s0 = __shfl(s_l, j,     32);
            int   s1 = __shfl(s_l, j + 1, 32);
            int   s2 = __shfl(s_l, j + 2, 32);
            int   s3 = __shfl(s_l, j + 3, 32);
            float w0 = __shfl(w_l, j,     32);
            float w1 = __shfl(w_l, j + 1, 32);
            float w2 = __shfl(w_l, j + 2, 32);
            float w3 = __shfl(w_l, j + 3, 32);
            if (ch) {
                ushort4 u0 = ((const ushort4*)(tab + (long long)s0 * D_FEAT))[lane];
                ushort4 u1 = ((const ushort4*)(tab + (long long)s1 * D_FEAT))[lane];
                ushort4 u2 = ((const ushort4*)(tab + (long long)s2 * D_FEAT))[lane];
                ushort4 u3 = ((const ushort4*)(tab + (long long)s3 * D_FEAT))[lane];
                acc.x = fmaf(bf2f(u0.x), w0, fmaf(bf2f(u1.x), w1, fmaf(bf2f(u2.x), w2, fmaf(bf2f(u3.x), w3, acc.x))));
                acc.y = fmaf(bf2f(u0.y), w0, fmaf(bf2f(u1.y), w1, fmaf(bf2f(u2.y), w2, fmaf(bf2f(u3.y), w3, acc.y))));
                acc.z = fmaf(bf2f(u0.z), w0, fmaf(bf2f(u1.z), w1, fmaf(bf2f(u2.z), w2, fmaf(bf2f(u3.z), w3, acc.z))));
                acc.w = fmaf(bf2f(u0.w), w0, fmaf(bf2f(u1.w), w1, fmaf(bf2f(u2.w), w2, fmaf(bf2f(u3.w), w3, acc.w))));
            }
        }
        for (; j < m; ++j) {
            int   s = __shfl(s_l, j, 32);
            float w = __shfl(w_l, j, 32);
            if (ch) {
                ushort4 u = ((const ushort4*)(tab + (long long)s * D_FEAT))[lane];
                acc.x = fmaf(bf2f(u.x), w, acc.x);
                acc.y = fmaf(bf2f(u.y), w, acc.y);
                acc.z = fmaf(bf2f(u.z), w, acc.z);
                acc.w = fmaf(bf2f(u.w), w, acc.w);
            }
        }
    }

    if (ch) {
        float r = lr[hop];
        ushort4 pu = ((const ushort4*)(tab + (long long)gid * D_FEAT))[lane];
        float4 o;
        o.x = acc.x * r + (1.0f - r) * bf2f(pu.x);
        o.y = acc.y * r + (1.0f - r) * bf2f(pu.y);
        o.z = acc.z * r + (1.0f - r) * bf2f(pu.z);
        o.w = acc.w * r + (1.0f - r) * bf2f(pu.w);
        ((float4*)(out + (long long)gid * OUT_STRIDE))[lane] = o;
        if (tab_next) {
            ushort4 ov;
            ov.x = f2bf(o.x); ov.y = f2bf(o.y); ov.z = f2bf(o.z); ov.w = f2bf(o.w);
            ((ushort4*)(tab_next + (long long)gid * D_FEAT))[lane] = ov;
        }
    }
}

extern "C" void kernel_launch(void* const* d_in, const int* in_sizes, int n_in,
                              void* d_out, int out_size, void* d_ws, size_t ws_size,
                              hipStream_t stream) {
    const float* h   = (const float*)d_in[0];
    const float* dn  = (const float*)d_in[1];
    const int*   src = (const int*)d_in[2];
    const int*   dst = (const int*)d_in[3];
    const float* lr  = (const float*)d_in[4];
    float* out = (float*)d_out;

    // workspace carve-up (16B-aligned chunks)
    char* base = (char*)d_ws;
    Edge* edges = (Edge*)base;              base += (size_t)N_EDGES * sizeof(Edge);
    unsigned short* tabA = (unsigned short*)base; base += (size_t)N_NODES * D_FEAT * sizeof(unsigned short);
    unsigned short* tabB = (unsigned short*)base; base += (size_t)N_NODES * D_FEAT * sizeof(unsigned short);
    int* off      = (int*)base;             base += (N_NODES + 1) * sizeof(int);
    int* deg      = (int*)base;             base += N_NODES * sizeof(int);
    int* partials = (int*)base;             base += NBLK_SCAN * sizeof(int);

    const int EB = (N_EDGES + 255) / 256;

    hipMemsetAsync(deg, 0, N_NODES * sizeof(int), stream);
    hist_kernel<<<EB, 256, 0, stream>>>(dst, deg);
    scanA_kernel<<<NBLK_SCAN, SCAN_B, 0, stream>>>(deg, off, partials);
    scanB_kernel<<<1, SCAN_B, 0, stream>>>(partials);
    scanC_kernel<<<NBLK_SCAN, SCAN_B, 0, stream>>>(off, partials, deg);
    scatter_kernel<<<EB, 256, 0, stream>>>(src, dst, dn, off, deg, edges);
    f32_to_bf16_kernel<<<(N_NODES * D_FEAT / 4 + 255) / 256, 256, 0, stream>>>(h, tabA);

    // 4 fused hops (bf16 ping-pong tables)
    const int GROUPS_PER_BLOCK = 8;  // 256 threads = 8 x 32-lane groups
    const int HB = (N_NODES + GROUPS_PER_BLOCK - 1) / GROUPS_PER_BLOCK;
    unsigned short* cur = tabA;
    unsigned short* nxt = tabB;
    for (int hop = 0; hop < HOP_NUM; ++hop) {
        unsigned short* wr = (hop == HOP_NUM - 1) ? (unsigned short*)nullptr : nxt;
        spmm_gather_kernel<<<HB, 256, 0, stream>>>(cur, off, edges, lr, hop,
                                                   out + hop * D_FEAT, wr);
        unsigned short* t = cur; cur = nxt; nxt = t;
    }
}

// Round 6
// 214.501 us; speedup vs baseline: 18.8505x; 1.0180x over previous
//
#include <hip/hip_runtime.h>

#define N_NODES 50000
#define N_EDGES 800000
#define D_FEAT 96
#define HOP_NUM 4
#define OUT_STRIDE (HOP_NUM * D_FEAT)
#define SCAN_B 256
#define NBLK_SCAN ((N_NODES + SCAN_B - 1) / SCAN_B)  // 196

struct Edge { int s; float w; };

__device__ __forceinline__ unsigned short f2bf(float x) {
    union { float f; unsigned u; } c; c.f = x;
    unsigned r = (c.u + 0x7FFFu + ((c.u >> 16) & 1u)) >> 16;  // RNE
    return (unsigned short)r;
}
__device__ __forceinline__ float bf2f(unsigned short b) {
    union { unsigned u; float f; } c; c.u = ((unsigned)b) << 16;
    return c.f;
}

// ---------- CSR build (once per launch) ----------

__global__ void zero_deg_kernel(int* __restrict__ deg) {
    int i = blockIdx.x * blockDim.x + threadIdx.x;
    if (i < N_NODES) deg[i] = 0;
}

__global__ void hist_kernel(const int* __restrict__ dst, int* __restrict__ deg) {
    int e = blockIdx.x * blockDim.x + threadIdx.x;
    if (e >= N_EDGES) return;
    atomicAdd(&deg[dst[e]], 1);
}

__global__ void scanA_kernel(const int* __restrict__ deg, int* __restrict__ off,
                             int* __restrict__ partials) {
    int i = blockIdx.x * SCAN_B + threadIdx.x;
    int v = (i < N_NODES) ? deg[i] : 0;
    int lane = threadIdx.x & 63;
    int wid  = threadIdx.x >> 6;
    int x = v;
    #pragma unroll
    for (int o = 1; o < 64; o <<= 1) {
        int y = __shfl_up(x, o, 64);
        if (lane >= o) x += y;
    }
    __shared__ int wtot[SCAN_B / 64];
    if (lane == 63) wtot[wid] = x;
    __syncthreads();
    int wbase = 0;
    #pragma unroll
    for (int w = 0; w < SCAN_B / 64; ++w) wbase += (w < wid) ? wtot[w] : 0;
    if (i < N_NODES) off[i] = wbase + x - v;
    if (threadIdx.x == SCAN_B - 1) partials[blockIdx.x] = wbase + x;
}

__global__ void scanB_kernel(int* __restrict__ partials) {
    int tid = threadIdx.x;  // 256 threads
    int v = (tid < NBLK_SCAN) ? partials[tid] : 0;
    int lane = tid & 63;
    int wid  = tid >> 6;
    int x = v;
    #pragma unroll
    for (int o = 1; o < 64; o <<= 1) {
        int y = __shfl_up(x, o, 64);
        if (lane >= o) x += y;
    }
    __shared__ int wtot[SCAN_B / 64];
    if (lane == 63) wtot[wid] = x;
    __syncthreads();
    int wbase = 0;
    #pragma unroll
    for (int w = 0; w < SCAN_B / 64; ++w) wbase += (w < wid) ? wtot[w] : 0;
    if (tid < NBLK_SCAN) partials[tid] = wbase + x - v;
}

__global__ void scanC_kernel(int* __restrict__ off, const int* __restrict__ partials,
                             int* __restrict__ cursor) {
    int i = blockIdx.x * SCAN_B + threadIdx.x;
    if (i < N_NODES) {
        off[i] += partials[blockIdx.x];
        cursor[i] = 0;
    }
    if (i == 0) off[N_NODES] = N_EDGES;
}

__global__ void scatter_kernel(const int* __restrict__ src, const int* __restrict__ dst,
                               const float* __restrict__ dn,
                               const int* __restrict__ off, int* __restrict__ cursor,
                               Edge* __restrict__ edges) {
    int e = blockIdx.x * blockDim.x + threadIdx.x;
    if (e >= N_EDGES) return;
    int t = dst[e];
    int s = src[e];
    float w = dn[s] * dn[t];
    int p = atomicAdd(&cursor[t], 1);
    Edge ed; ed.s = s; ed.w = w;
    edges[off[t] + p] = ed;
}

// seed: f32 features -> bf16 table
__global__ void f32_to_bf16_kernel(const float* __restrict__ in, unsigned short* __restrict__ out) {
    int i = blockIdx.x * blockDim.x + threadIdx.x;
    if (i >= N_NODES * D_FEAT / 4) return;
    float4 v = ((const float4*)in)[i];
    ushort4 o;
    o.x = f2bf(v.x); o.y = f2bf(v.y); o.z = f2bf(v.z); o.w = f2bf(v.w);
    ((ushort4*)out)[i] = o;
}

// ---------- fused per-hop SpMM + residual blend (bf16 gather table) ----------
// 32-lane group per dst node; lanes 0..23 own 4 channels (ushort4 = 8 B).
__global__ void spmm_gather_kernel(const unsigned short* __restrict__ tab,
                                   const int* __restrict__ off,
                                   const Edge* __restrict__ edges,
                                   const float* __restrict__ lr, int hop,
                                   float* __restrict__ out,
                                   unsigned short* __restrict__ tab_next) {
    int gid = (blockIdx.x * blockDim.x + threadIdx.x) >> 5;
    int lane = threadIdx.x & 31;
    if (gid >= N_NODES) return;
    int beg = off[gid];
    int end = off[gid + 1];
    const bool ch = (lane < 24);

    float4 acc = make_float4(0.f, 0.f, 0.f, 0.f);
    for (int b = beg; b < end; b += 32) {
        int m = min(32, end - b);
        int s_l = 0; float w_l = 0.f;
        if (lane < m) {
            Edge ed = edges[b + lane];
            s_l = ed.s; w_l = ed.w;
        }
        int j = 0;
        for (; j + 4 <= m; j += 4) {
            int   s0 = __shfl(s_l, j,     32);
            int   s1 = __shfl(s_l, j + 1, 32);
            int   s2 = __shfl(s_l, j + 2, 32);
            int   s3 = __shfl(s_l, j + 3, 32);
            float w0 = __shfl(w_l, j,     32);
            float w1 = __shfl(w_l, j + 1, 32);
            float w2 = __shfl(w_l, j + 2, 32);
            float w3 = __shfl(w_l, j + 3, 32);
            if (ch) {
                ushort4 u0 = ((const ushort4*)(tab + (long long)s0 * D_FEAT))[lane];
                ushort4 u1 = ((const ushort4*)(tab + (long long)s1 * D_FEAT))[lane];
                ushort4 u2 = ((const ushort4*)(tab + (long long)s2 * D_FEAT))[lane];
                ushort4 u3 = ((const ushort4*)(tab + (long long)s3 * D_FEAT))[lane];
                acc.x = fmaf(bf2f(u0.x), w0, fmaf(bf2f(u1.x), w1, fmaf(bf2f(u2.x), w2, fmaf(bf2f(u3.x), w3, acc.x))));
                acc.y = fmaf(bf2f(u0.y), w0, fmaf(bf2f(u1.y), w1, fmaf(bf2f(u2.y), w2, fmaf(bf2f(u3.y), w3, acc.y))));
                acc.z = fmaf(bf2f(u0.z), w0, fmaf(bf2f(u1.z), w1, fmaf(bf2f(u2.z), w2, fmaf(bf2f(u3.z), w3, acc.z))));
                acc.w = fmaf(bf2f(u0.w), w0, fmaf(bf2f(u1.w), w1, fmaf(bf2f(u2.w), w2, fmaf(bf2f(u3.w), w3, acc.w))));
            }
        }
        for (; j < m; ++j) {
            int   s = __shfl(s_l, j, 32);
            float w = __shfl(w_l, j, 32);
            if (ch) {
                ushort4 u = ((const ushort4*)(tab + (long long)s * D_FEAT))[lane];
                acc.x = fmaf(bf2f(u.x), w, acc.x);
                acc.y = fmaf(bf2f(u.y), w, acc.y);
                acc.z = fmaf(bf2f(u.z), w, acc.z);
                acc.w = fmaf(bf2f(u.w), w, acc.w);
            }
        }
    }

    if (ch) {
        float r = lr[hop];
        ushort4 pu = ((const ushort4*)(tab + (long long)gid * D_FEAT))[lane];
        float4 o;
        o.x = acc.x * r + (1.0f - r) * bf2f(pu.x);
        o.y = acc.y * r + (1.0f - r) * bf2f(pu.y);
        o.z = acc.z * r + (1.0f - r) * bf2f(pu.z);
        o.w = acc.w * r + (1.0f - r) * bf2f(pu.w);
        ((float4*)(out + (long long)gid * OUT_STRIDE))[lane] = o;
        if (tab_next) {
            ushort4 ov;
            ov.x = f2bf(o.x); ov.y = f2bf(o.y); ov.z = f2bf(o.z); ov.w = f2bf(o.w);
            ((ushort4*)(tab_next + (long long)gid * D_FEAT))[lane] = ov;
        }
    }
}

extern "C" void kernel_launch(void* const* d_in, const int* in_sizes, int n_in,
                              void* d_out, int out_size, void* d_ws, size_t ws_size,
                              hipStream_t stream) {
    const float* h   = (const float*)d_in[0];
    const float* dn  = (const float*)d_in[1];
    const int*   src = (const int*)d_in[2];
    const int*   dst = (const int*)d_in[3];
    const float* lr  = (const float*)d_in[4];
    float* out = (float*)d_out;

    // workspace carve-up (16B-aligned chunks)
    char* base = (char*)d_ws;
    Edge* edges = (Edge*)base;              base += (size_t)N_EDGES * sizeof(Edge);
    unsigned short* tabA = (unsigned short*)base; base += (size_t)N_NODES * D_FEAT * sizeof(unsigned short);
    unsigned short* tabB = (unsigned short*)base; base += (size_t)N_NODES * D_FEAT * sizeof(unsigned short);
    int* off      = (int*)base;             base += (N_NODES + 1) * sizeof(int);
    int* deg      = (int*)base;             base += N_NODES * sizeof(int);
    int* partials = (int*)base;             base += NBLK_SCAN * sizeof(int);

    const int EB = (N_EDGES + 255) / 256;

    zero_deg_kernel<<<NBLK_SCAN, SCAN_B, 0, stream>>>(deg);
    hist_kernel<<<EB, 256, 0, stream>>>(dst, deg);
    scanA_kernel<<<NBLK_SCAN, SCAN_B, 0, stream>>>(deg, off, partials);
    scanB_kernel<<<1, SCAN_B, 0, stream>>>(partials);
    scanC_kernel<<<NBLK_SCAN, SCAN_B, 0, stream>>>(off, partials, deg);
    scatter_kernel<<<EB, 256, 0, stream>>>(src, dst, dn, off, deg, edges);
    f32_to_bf16_kernel<<<(N_NODES * D_FEAT / 4 + 255) / 256, 256, 0, stream>>>(h, tabA);

    // 4 fused hops (bf16 ping-pong tables)
    const int GROUPS_PER_BLOCK = 8;  // 256 threads = 8 x 32-lane groups
    const int HB = (N_NODES + GROUPS_PER_BLOCK - 1) / GROUPS_PER_BLOCK;
    unsigned short* cur = tabA;
    unsigned short* nxt = tabB;
    for (int hop = 0; hop < HOP_NUM; ++hop) {
        unsigned short* wr = (hop == HOP_NUM - 1) ? (unsigned short*)nullptr : nxt;
        spmm_gather_kernel<<<HB, 256, 0, stream>>>(cur, off, edges, lr, hop,
                                                   out + hop * D_FEAT, wr);
        unsigned short* t = cur; cur = nxt; nxt = t;
    }
}